// Round 4
// baseline (421.169 us; speedup 1.0000x reference)
//
#include <hip/hip_runtime.h>
#include <math.h>

#define NB   8
#define LLEN 2048
#define HDIM 1024
#define LNEPS 1e-5f

#define BM 256
#define BN 256
#define BK 64
#define NT_K (HDIM / BK)   // 16 K-tiles
#define NTHR 512
#define SLOT (BM * BK)     // 16384 shorts = 32 KiB per operand slot

typedef __attribute__((ext_vector_type(8))) short short8;
typedef __attribute__((ext_vector_type(4))) unsigned short ushort4v;
typedef __attribute__((ext_vector_type(4))) float f32x4;

typedef __attribute__((address_space(3))) void lds_void;
typedef const __attribute__((address_space(1))) void glob_void;

__device__ __forceinline__ unsigned short f2bf(float f) {
    union { float f; unsigned u; } v; v.f = f;
    unsigned r = v.u + 0x7FFFu + ((v.u >> 16) & 1u);
    return (unsigned short)(r >> 16);
}
__device__ __forceinline__ float bf2f(unsigned short h) {
    union { unsigned u; float f; } v; v.u = ((unsigned)h) << 16;
    return v.f;
}

__device__ __forceinline__ void wg_barrier() {
    asm volatile("" ::: "memory");
    __builtin_amdgcn_s_barrier();
    asm volatile("" ::: "memory");
}

// One fill step: stages 64 rows (s-th quarter) of a 256x64 bf16 tile into an
// LDS slot with XOR-swizzled layout byte(r,cb) = r*128 + (cb ^ ((r&7)<<4)).
// global_load_lds writes linearly, so the swizzle is pre-applied to the
// per-lane GLOBAL source column (rule 21).
__device__ __forceinline__ void fill_one(
    const unsigned short* __restrict__ src, int R0, int kcol,
    unsigned short* slot, int s, int w, int l)
{
    const int rsub = l >> 3;
    const int csw = 8 * ((l & 7) ^ rsub);
    const int r = (s*8 + w)*8 + rsub;
    __builtin_amdgcn_global_load_lds(
        (glob_void*)(src + (size_t)(R0 + r) * HDIM + kcol + csw),
        (lds_void*)(slot + (s*8 + w)*512), 16, 0, 0);
}

#define MFMA_CLUSTER(MI)                                                        \
    wg_barrier();                                                               \
    __builtin_amdgcn_s_setprio(1);                                              \
    _Pragma("unroll")                                                           \
    for (int ni = 0; ni < 4; ++ni) {                                            \
        acc[MI][ni]   = __builtin_amdgcn_mfma_f32_16x16x32_bf16(a0, bfr[ni][0], acc[MI][ni],   0,0,0); \
        acc[MI][ni]   = __builtin_amdgcn_mfma_f32_16x16x32_bf16(a1, bfr[ni][1], acc[MI][ni],   0,0,0); \
        acc[MI+1][ni] = __builtin_amdgcn_mfma_f32_16x16x32_bf16(a2, bfr[ni][0], acc[MI+1][ni], 0,0,0); \
        acc[MI+1][ni] = __builtin_amdgcn_mfma_f32_16x16x32_bf16(a3, bfr[ni][1], acc[MI+1][ni], 0,0,0); \
    }                                                                           \
    __builtin_amdgcn_s_setprio(0);

// 4-phase-per-K-tile pipelined MFMA loop. A: rows [rowBase,+256) of srcA,
// B: rows [colBase,+256) of srcB, both K=HDIM, NT grid of BK=64 tiles.
__device__ __forceinline__ void run_pipeline(
    const unsigned short* __restrict__ srcA,
    const unsigned short* __restrict__ srcB,
    int rowBase, int colBase,
    unsigned short* lds, f32x4 (&acc)[8][4])
{
    const int t = threadIdx.x, w = t >> 6, l = t & 63;
    const int wr = w >> 2, wc = w & 3;
    const int lr = l & 15;
    const int sw = (l & 7) << 4;
    const int aRB = (wr*128 + lr) * 128;
    const int bRB = (wc*64  + lr) * 128;
    const int c0 = ((l >> 4) * 16) ^ sw;
    const int c1 = (64 + ((l >> 4) * 16)) ^ sw;

    unsigned short* sA[2] = { lds,            lds + 2*SLOT };
    unsigned short* sB[2] = { lds + SLOT,     lds + 3*SLOT };

    // prologue: tile 0 -> buffer 0, drain, barrier
    #pragma unroll
    for (int s = 0; s < 4; ++s) fill_one(srcA, rowBase, 0, sA[0], s, w, l);
    #pragma unroll
    for (int s = 0; s < 4; ++s) fill_one(srcB, colBase, 0, sB[0], s, w, l);
    asm volatile("s_waitcnt vmcnt(0)" ::: "memory");
    wg_barrier();

    short8 bfr[4][2];

    for (int kt = 0; kt < NT_K; ++kt) {
        const int cur = kt & 1, nxt = cur ^ 1;
        const char* bufA = (const char*)sA[cur];
        const char* bufB = (const char*)sB[cur];
        const int kn = (kt + 1 < NT_K ? kt + 1 : kt) * BK;  // clamped tail

        // ---- phase 0: quadrant mi{0,1}; fills B s0,s1; ds: B(8)+A(4) ----
        {
            fill_one(srcB, colBase, kn, sB[nxt], 0, w, l);
            fill_one(srcB, colBase, kn, sB[nxt], 1, w, l);
            short8 a0 = *(const short8*)(bufA + aRB + 0*2048 + c0);
            short8 a1 = *(const short8*)(bufA + aRB + 0*2048 + c1);
            short8 a2 = *(const short8*)(bufA + aRB + 1*2048 + c0);
            short8 a3 = *(const short8*)(bufA + aRB + 1*2048 + c1);
            #pragma unroll
            for (int ni = 0; ni < 4; ++ni) {
                bfr[ni][0] = *(const short8*)(bufB + bRB + ni*2048 + c0);
                bfr[ni][1] = *(const short8*)(bufB + bRB + ni*2048 + c1);
            }
            MFMA_CLUSTER(0)
            wg_barrier();
        }
        // ---- phase 1: quadrant mi{2,3}; fills B s2,s3; vmcnt(4) ----
        {
            fill_one(srcB, colBase, kn, sB[nxt], 2, w, l);
            fill_one(srcB, colBase, kn, sB[nxt], 3, w, l);
            short8 a0 = *(const short8*)(bufA + aRB + 2*2048 + c0);
            short8 a1 = *(const short8*)(bufA + aRB + 2*2048 + c1);
            short8 a2 = *(const short8*)(bufA + aRB + 3*2048 + c0);
            short8 a3 = *(const short8*)(bufA + aRB + 3*2048 + c1);
            MFMA_CLUSTER(2)
            // wait: this tile's A s1,s3 (issued prev tile ph3) are the 2 oldest
            asm volatile("s_waitcnt vmcnt(4)" ::: "memory");
            wg_barrier();
        }
        // ---- phase 2: quadrant mi{4,5}; fills A s0,s2 ----
        {
            fill_one(srcA, rowBase, kn, sA[nxt], 0, w, l);
            fill_one(srcA, rowBase, kn, sA[nxt], 2, w, l);
            short8 a0 = *(const short8*)(bufA + aRB + 4*2048 + c0);
            short8 a1 = *(const short8*)(bufA + aRB + 4*2048 + c1);
            short8 a2 = *(const short8*)(bufA + aRB + 5*2048 + c0);
            short8 a3 = *(const short8*)(bufA + aRB + 5*2048 + c1);
            MFMA_CLUSTER(4)
            wg_barrier();
        }
        // ---- phase 3: quadrant mi{6,7}; fills A s1,s3; vmcnt(2) ----
        {
            fill_one(srcA, rowBase, kn, sA[nxt], 1, w, l);
            fill_one(srcA, rowBase, kn, sA[nxt], 3, w, l);
            short8 a0 = *(const short8*)(bufA + aRB + 6*2048 + c0);
            short8 a1 = *(const short8*)(bufA + aRB + 6*2048 + c1);
            short8 a2 = *(const short8*)(bufA + aRB + 7*2048 + c0);
            short8 a3 = *(const short8*)(bufA + aRB + 7*2048 + c1);
            MFMA_CLUSTER(6)
            // wait: next tile's B s0..s3 + A s0,s2 (6 oldest) landed
            asm volatile("s_waitcnt vmcnt(2)" ::: "memory");
            wg_barrier();
        }
    }
    asm volatile("s_waitcnt vmcnt(0)" ::: "memory");
}

// ---- fused projection GEMM: C_mat = bf16(alpha_mat * (A @ Bt^T + bias_mat)) ----
// Bt rows [0,3*HDIM) may span 3 weight matrices; block's 256-col tile lies in one.
__global__ __launch_bounds__(NTHR, 2) void gemm_proj(
    const unsigned short* __restrict__ A,
    const unsigned short* __restrict__ Bt,
    const float* __restrict__ bias0, const float* __restrict__ bias1,
    const float* __restrict__ bias2,
    unsigned short* __restrict__ C0, unsigned short* __restrict__ C1,
    unsigned short* __restrict__ C2,
    float al0, float al1, float al2, int gx)
{
    __shared__ __align__(16) unsigned short lds[4 * SLOT];
    const int nwg = gridDim.x, bid = blockIdx.x;
    const int swz = (bid & 7) * (nwg >> 3) + (bid >> 3);
    const int bx = swz % gx, by = swz / gx;
    const int rowBase = by * BM, colBase = bx * BN;

    f32x4 acc[8][4] = {};
    run_pipeline(A, Bt, rowBase, colBase, lds, acc);

    const int t = threadIdx.x, w = t >> 6, l = t & 63;
    const int wr = w >> 2, wc = w & 3;
    const int lr = l & 15;

    const int mat = colBase >> 10;
    unsigned short* Cm = (mat == 0) ? C0 : (mat == 1 ? C1 : C2);
    const float* bm    = (mat == 0) ? bias0 : (mat == 1 ? bias1 : bias2);
    const float am     = (mat == 0) ? al0 : (mat == 1 ? al1 : al2);
    const int lcb = colBase & (HDIM - 1);

    #pragma unroll
    for (int ni = 0; ni < 4; ++ni) {
        const int col = lcb + wc*64 + ni*16 + lr;
        const float bv = bm[col];
        #pragma unroll
        for (int mi = 0; mi < 8; ++mi) {
            const int row0 = rowBase + wr*128 + mi*16 + (l >> 4) * 4;
            #pragma unroll
            for (int j = 0; j < 4; ++j)
                Cm[(size_t)(row0 + j) * HDIM + col] = f2bf(am * (acc[mi][ni][j] + bv));
        }
    }
}

// ---- per batch: A[a,b]=Q[a,:]·K[b,:]; colsum[b]+=sum_a exp(A[a,b]); diag[l]=A[l,l] ----
__global__ __launch_bounds__(NTHR, 2) void qk_colsum_diag_256(
    const unsigned short* __restrict__ Q,
    const unsigned short* __restrict__ K,
    float* __restrict__ colsum, float* __restrict__ diagv)
{
    __shared__ __align__(16) unsigned short lds[4 * SLOT];
    const int n = blockIdx.z;
    const unsigned short* Qn = Q + (size_t)n * LLEN * HDIM;
    const unsigned short* Kn = K + (size_t)n * LLEN * HDIM;
    const int rowBase = blockIdx.y * BM;
    const int colBase = blockIdx.x * BN;

    f32x4 acc[8][4] = {};
    run_pipeline(Qn, Kn, rowBase, colBase, lds, acc);

    const int t = threadIdx.x, w = t >> 6, l = t & 63;
    const int wr = w >> 2, wc = w & 3;
    const int lr = l & 15;

    // column sums of exp over this wave's 128 rows
    #pragma unroll
    for (int ni = 0; ni < 4; ++ni) {
        float s = 0.f;
        #pragma unroll
        for (int mi = 0; mi < 8; ++mi)
            #pragma unroll
            for (int j = 0; j < 4; ++j)
                s += __expf(acc[mi][ni][j]);
        s += __shfl_xor(s, 16);
        s += __shfl_xor(s, 32);
        if (l < 16)
            atomicAdd(&colsum[(size_t)n * LLEN + colBase + wc*64 + ni*16 + l], s);
    }

    // diagonal entries (pre-exp)
    if (rowBase == colBase && (wc >> 1) == wr) {
        #pragma unroll
        for (int mi = 0; mi < 8; ++mi)
            #pragma unroll
            for (int ni = 0; ni < 4; ++ni)
                #pragma unroll
                for (int j = 0; j < 4; ++j) {
                    const int rr = wr*128 + mi*16 + (l >> 4)*4 + j;
                    const int cc = wc*64 + ni*16 + lr;
                    if (rr == cc)
                        diagv[(size_t)n * LLEN + rowBase + rr] = acc[mi][ni][j];
                }
    }
}

// ---- fp32 -> bf16 cast, 8 elems/thread ----
__global__ __launch_bounds__(256) void cast_f32_bf16(
    const float* __restrict__ in, unsigned short* __restrict__ outp, int n8)
{
    int i = blockIdx.x * 256 + threadIdx.x;
    if (i >= n8) return;
    const float4* p = reinterpret_cast<const float4*>(in) + (size_t)i * 2;
    float4 a = p[0], b = p[1];
    short8 o;
    o[0] = (short)f2bf(a.x); o[1] = (short)f2bf(a.y);
    o[2] = (short)f2bf(a.z); o[3] = (short)f2bf(a.w);
    o[4] = (short)f2bf(b.x); o[5] = (short)f2bf(b.y);
    o[6] = (short)f2bf(b.z); o[7] = (short)f2bf(b.w);
    *(reinterpret_cast<short8*>(outp) + i) = o;
}

// ---- W (K x N fp32) -> Wt (N x K bf16) ----
__global__ __launch_bounds__(256) void transpose_cast(
    const float* __restrict__ W, unsigned short* __restrict__ Wt)
{
    __shared__ float tile[32][33];
    const int tx = threadIdx.x & 31, ty = threadIdx.x >> 5;
    const int c0 = blockIdx.x * 32, r0 = blockIdx.y * 32;
    #pragma unroll
    for (int r = 0; r < 4; ++r)
        tile[ty + r*8][tx] = W[(size_t)(r0 + ty + r*8) * HDIM + c0 + tx];
    __syncthreads();
    #pragma unroll
    for (int r = 0; r < 4; ++r)
        Wt[(size_t)(c0 + ty + r*8) * HDIM + r0 + tx] = f2bf(tile[tx][ty + r*8]);
}

// ---- h1 = bf16( LN(diag*V + X) * g1 + b1 ) ----
__global__ __launch_bounds__(256) void ln1_kernel(
    const unsigned short* __restrict__ Vb, const float* __restrict__ X,
    const float* __restrict__ colsum, const float* __restrict__ diagval,
    const float* __restrict__ g1, const float* __restrict__ b1,
    unsigned short* __restrict__ h1)
{
    const int row = blockIdx.x;
    const size_t base = (size_t)row * HDIM;
    const float dv = __expf(diagval[row]) / colsum[row];
    const int h0 = threadIdx.x * 4;

    ushort4v vv = *reinterpret_cast<const ushort4v*>(&Vb[base + h0]);
    float4 xx = *reinterpret_cast<const float4*>(&X[base + h0]);
    float y[4];
    y[0] = dv * bf2f(vv[0]) + xx.x; y[1] = dv * bf2f(vv[1]) + xx.y;
    y[2] = dv * bf2f(vv[2]) + xx.z; y[3] = dv * bf2f(vv[3]) + xx.w;

    float s = y[0]+y[1]+y[2]+y[3];
    float s2 = y[0]*y[0]+y[1]*y[1]+y[2]*y[2]+y[3]*y[3];
    #pragma unroll
    for (int off = 32; off > 0; off >>= 1) {
        s  += __shfl_down(s,  off);
        s2 += __shfl_down(s2, off);
    }
    __shared__ float ws1[4], ws2[4];
    const int wid = threadIdx.x >> 6;
    if ((threadIdx.x & 63) == 0) { ws1[wid] = s; ws2[wid] = s2; }
    __syncthreads();
    const float S  = ws1[0]+ws1[1]+ws1[2]+ws1[3];
    const float S2 = ws2[0]+ws2[1]+ws2[2]+ws2[3];
    const float m   = S  * (1.0f / HDIM);
    const float var = S2 * (1.0f / HDIM) - m*m;
    const float inv = rsqrtf(var + LNEPS);

    float4 gg = *reinterpret_cast<const float4*>(&g1[h0]);
    float4 bb = *reinterpret_cast<const float4*>(&b1[h0]);
    ushort4v o;
    o[0] = f2bf((y[0]-m)*inv*gg.x + bb.x);
    o[1] = f2bf((y[1]-m)*inv*gg.y + bb.y);
    o[2] = f2bf((y[2]-m)*inv*gg.z + bb.z);
    o[3] = f2bf((y[3]-m)*inv*gg.w + bb.w);
    *reinterpret_cast<ushort4v*>(&h1[base + h0]) = o;
}

// ---- out = fp32( LN(G + h1) * g2 + b2 ) ----
__global__ __launch_bounds__(256) void ln2_kernel(
    const unsigned short* __restrict__ Gb, const unsigned short* __restrict__ h1b,
    const float* __restrict__ g2, const float* __restrict__ b2,
    float* __restrict__ out)
{
    const int row = blockIdx.x;
    const size_t base = (size_t)row * HDIM;
    const int h0 = threadIdx.x * 4;

    ushort4v gv = *reinterpret_cast<const ushort4v*>(&Gb[base + h0]);
    ushort4v hv = *reinterpret_cast<const ushort4v*>(&h1b[base + h0]);
    float y[4];
    y[0] = bf2f(gv[0]) + bf2f(hv[0]); y[1] = bf2f(gv[1]) + bf2f(hv[1]);
    y[2] = bf2f(gv[2]) + bf2f(hv[2]); y[3] = bf2f(gv[3]) + bf2f(hv[3]);

    float s = y[0]+y[1]+y[2]+y[3];
    float s2 = y[0]*y[0]+y[1]*y[1]+y[2]*y[2]+y[3]*y[3];
    #pragma unroll
    for (int off = 32; off > 0; off >>= 1) {
        s  += __shfl_down(s,  off);
        s2 += __shfl_down(s2, off);
    }
    __shared__ float ws1[4], ws2[4];
    const int wid = threadIdx.x >> 6;
    if ((threadIdx.x & 63) == 0) { ws1[wid] = s; ws2[wid] = s2; }
    __syncthreads();
    const float S  = ws1[0]+ws1[1]+ws1[2]+ws1[3];
    const float S2 = ws2[0]+ws2[1]+ws2[2]+ws2[3];
    const float m   = S  * (1.0f / HDIM);
    const float var = S2 * (1.0f / HDIM) - m*m;
    const float inv = rsqrtf(var + LNEPS);

    float4 gg = *reinterpret_cast<const float4*>(&g2[h0]);
    float4 bb = *reinterpret_cast<const float4*>(&b2[h0]);
    float4 o;
    o.x = (y[0]-m)*inv*gg.x + bb.x;
    o.y = (y[1]-m)*inv*gg.y + bb.y;
    o.z = (y[2]-m)*inv*gg.z + bb.z;
    o.w = (y[3]-m)*inv*gg.w + bb.w;
    *reinterpret_cast<float4*>(&out[base + h0]) = o;
}

extern "C" void kernel_launch(void* const* d_in, const int* in_sizes, int n_in,
                              void* d_out, int out_size, void* d_ws, size_t ws_size,
                              hipStream_t stream) {
    (void)in_sizes; (void)n_in; (void)out_size; (void)ws_size;
    const float* X  = (const float*)d_in[0];
    const float* Wq = (const float*)d_in[1];
    const float* bq = (const float*)d_in[2];
    const float* Wk = (const float*)d_in[3];
    const float* bk = (const float*)d_in[4];
    const float* Wv = (const float*)d_in[5];
    const float* bv = (const float*)d_in[6];
    const float* Wf = (const float*)d_in[7];
    const float* bf = (const float*)d_in[8];
    const float* g1 = (const float*)d_in[9];
    const float* b1 = (const float*)d_in[10];
    const float* g2 = (const float*)d_in[11];
    const float* b2 = (const float*)d_in[12];
    float* out = (float*)d_out;

    const size_t MATE = (size_t)NB * LLEN * HDIM;   // 16,777,216 elements
    const size_t WE   = (size_t)HDIM * HDIM;

    // d_out (64 MiB) doubles as staging: Xb bf16 [0,32MiB), Vb bf16 [32,64MiB).
    unsigned short* Xb  = (unsigned short*)d_out;
    unsigned short* Vb  = Xb + MATE;

    unsigned short* Qb  = (unsigned short*)d_ws;    // 32 MiB
    unsigned short* Kb  = Qb + MATE;                // 32 MiB
    unsigned short* WqT = Kb + MATE;                // contiguous 3*WE: [WqT|WkT|WvT]
    unsigned short* WkT = WqT + WE;
    unsigned short* WvT = WkT + WE;
    unsigned short* WfT = WvT + WE;
    float* colsum = (float*)(WfT + WE);             // 64 KiB
    float* diagv  = colsum + (size_t)NB * LLEN;     // 64 KiB
    unsigned short* h1b = Qb;                       // reuse after qk
    unsigned short* Gb  = Kb;                       // reuse after qk

    const int M = NB * LLEN;            // 16384
    const float scale = 1.0f / 32.0f;   // 1/sqrt(H)

    hipMemsetAsync(colsum, 0, (size_t)NB * LLEN * sizeof(float), stream);

    const int n8 = (int)(MATE / 8);
    cast_f32_bf16<<<n8 / 256, 256, 0, stream>>>(X, Xb, n8);

    dim3 tgrid(HDIM / 32, HDIM / 32);
    transpose_cast<<<tgrid, 256, 0, stream>>>(Wq, WqT);
    transpose_cast<<<tgrid, 256, 0, stream>>>(Wk, WkT);
    transpose_cast<<<tgrid, 256, 0, stream>>>(Wv, WvT);
    transpose_cast<<<tgrid, 256, 0, stream>>>(Wf, WfT);

    // fused QKV projection: B rows 0-3071 = [WqT|WkT|WvT]
    {
        const int gx = 3 * HDIM / BN;       // 12
        const int nwg = gx * (M / BM);      // 768 (%8==0, swizzle bijective)
        gemm_proj<<<nwg, NTHR, 0, stream>>>(Xb, WqT, bq, bk, bv,
                                            Qb, Kb, Vb, scale, scale, 1.0f, gx);
    }

    dim3 qgrid(LLEN / BN, LLEN / BM, NB);   // (8, 8, 8)
    qk_colsum_diag_256<<<qgrid, NTHR, 0, stream>>>(Qb, Kb, colsum, diagv);

    ln1_kernel<<<M, 256, 0, stream>>>(Vb, X, colsum, diagv, g1, b1, h1b);

    // FF GEMM: single-matrix path (mat always 0)
    {
        const int gx = HDIM / BN;           // 4
        const int nwg = gx * (M / BM);      // 256
        gemm_proj<<<nwg, NTHR, 0, stream>>>(h1b, WfT, bf, bf, bf,
                                            Gb, Gb, Gb, 1.0f, 1.0f, 1.0f, gx);
    }

    ln2_kernel<<<M, 256, 0, stream>>>(Gb, h1b, g2, b2, out);
}